// Round 2
// baseline (90.017 us; speedup 1.0000x reference)
//
#include <hip/hip_runtime.h>

// Problem: inputs [8192, 8192] f32. Semantics: idx = nonzero(x); out = idx.sum(0) -> int64 [2]
//   out[0] = sum of row-index i over all nonzero elements
//   out[1] = sum of col-index j over all nonzero elements
// Harness reads d_out as int32 (int64 ref wrapped via astype(np.int32)) -> write low 32 bits.

#define DIM0 8192u
#define DIM1 8192u

__global__ __launch_bounds__(256) void nz_idx_sum_kernel(
    const float4* __restrict__ in, unsigned long long* __restrict__ ws) {
    const unsigned nthreads = gridDim.x * blockDim.x;
    const unsigned N4 = (DIM0 * DIM1) / 4u;  // 16777216 float4s
    unsigned q = blockIdx.x * blockDim.x + threadIdx.x;

    unsigned si = 0, sj = 0;  // per-thread partials fit in u32 (max ~1.05e6)
    for (; q < N4; q += nthreads) {
        float4 v = in[q];
        unsigned i  = q >> 11;               // row index: q / (8192/4)
        unsigned jb = (q << 2) & (DIM1 - 1); // col index of v.x
        if (v.x != 0.0f) { si += i; sj += jb;     }
        if (v.y != 0.0f) { si += i; sj += jb + 1; }
        if (v.z != 0.0f) { si += i; sj += jb + 2; }
        if (v.w != 0.0f) { si += i; sj += jb + 3; }
    }

    // wave64 reduce (u32; wave partial max ~6.7e7, fits)
    for (int off = 32; off > 0; off >>= 1) {
        si += __shfl_down(si, off, 64);
        sj += __shfl_down(sj, off, 64);
    }

    __shared__ unsigned s_i[4], s_j[4];
    const int wave = threadIdx.x >> 6;
    const int lane = threadIdx.x & 63;
    if (lane == 0) { s_i[wave] = si; s_j[wave] = sj; }
    __syncthreads();

    if (threadIdx.x == 0) {
        unsigned long long ti = 0, tj = 0;
        for (int w = 0; w < 4; ++w) { ti += (unsigned long long)s_i[w]; tj += (unsigned long long)s_j[w]; }
        atomicAdd(&ws[0], ti);  // device-scope by default — safe across XCDs
        atomicAdd(&ws[1], tj);
    }
}

__global__ void nz_finalize(const unsigned long long* __restrict__ ws,
                            int* __restrict__ out) {
    if (threadIdx.x == 0 && blockIdx.x == 0) {
        // int64 -> int32 wrap (two's complement), matching numpy astype(np.int32)
        out[0] = (int)(unsigned)(ws[0] & 0xFFFFFFFFull);
        out[1] = (int)(unsigned)(ws[1] & 0xFFFFFFFFull);
    }
}

extern "C" void kernel_launch(void* const* d_in, const int* in_sizes, int n_in,
                              void* d_out, int out_size, void* d_ws, size_t ws_size,
                              hipStream_t stream) {
    const float4* in = (const float4*)d_in[0];
    unsigned long long* ws = (unsigned long long*)d_ws;
    int* out = (int*)d_out;

    // zero the two u64 accumulators every call (deterministic; capture-safe)
    hipMemsetAsync(d_ws, 0, 2 * sizeof(unsigned long long), stream);

    // 2048 blocks x 256 threads = 524288 threads; 32 float4s per thread exactly
    nz_idx_sum_kernel<<<2048, 256, 0, stream>>>(in, ws);
    nz_finalize<<<1, 64, 0, stream>>>(ws, out);
}

// Round 3
// 79.614 us; speedup vs baseline: 1.1307x; 1.1307x over previous
//
#include <hip/hip_runtime.h>

// Problem: inputs [8192, 8192] f32. Semantics: idx = nonzero(x); out = idx.sum(0) -> int64 [2]
//   out[0] = sum of row-index i over all nonzero elements
//   out[1] = sum of col-index j over all nonzero elements
// Harness reads d_out as int32 (int64 ref wrapped via astype(np.int32)) -> write low 32 bits.

#define DIM0 8192u
#define DIM1 8192u
#define NTHREADS (2048u * 256u)   // grid is fixed: 2048 blocks x 256 threads

__device__ __forceinline__ void nz_accum(float4 v, unsigned q,
                                         unsigned& si, unsigned& sj) {
    unsigned i  = q >> 11;               // row index: q / (8192/4)
    unsigned jb = (q << 2) & (DIM1 - 1); // col index of v.x
    if (v.x != 0.0f) { si += i; sj += jb;     }
    if (v.y != 0.0f) { si += i; sj += jb + 1; }
    if (v.z != 0.0f) { si += i; sj += jb + 2; }
    if (v.w != 0.0f) { si += i; sj += jb + 3; }
}

__global__ __launch_bounds__(256) void nz_idx_sum_kernel(
    const float4* __restrict__ in, unsigned long long* __restrict__ ws) {
    const unsigned N4 = (DIM0 * DIM1) / 4u;  // 16777216 float4s; 32 per thread
    const unsigned tid = blockIdx.x * blockDim.x + threadIdx.x;

    unsigned si = 0, sj = 0;  // per-thread partials fit in u32 (max ~1.05e6)

    // 8 outer iterations x 4 independent coalesced float4 loads -> 4 loads in flight
    for (unsigned b = tid; b < N4; b += 4u * NTHREADS) {
        float4 v0 = in[b];
        float4 v1 = in[b + NTHREADS];
        float4 v2 = in[b + 2u * NTHREADS];
        float4 v3 = in[b + 3u * NTHREADS];
        nz_accum(v0, b,                 si, sj);
        nz_accum(v1, b + NTHREADS,      si, sj);
        nz_accum(v2, b + 2u * NTHREADS, si, sj);
        nz_accum(v3, b + 3u * NTHREADS, si, sj);
    }

    // wave64 reduce (u32; wave partial max ~6.7e7, fits)
    for (int off = 32; off > 0; off >>= 1) {
        si += __shfl_down(si, off, 64);
        sj += __shfl_down(sj, off, 64);
    }

    __shared__ unsigned s_i[4], s_j[4];
    const int wave = threadIdx.x >> 6;
    const int lane = threadIdx.x & 63;
    if (lane == 0) { s_i[wave] = si; s_j[wave] = sj; }
    __syncthreads();

    if (threadIdx.x == 0) {
        unsigned long long ti = 0, tj = 0;
        for (int w = 0; w < 4; ++w) { ti += (unsigned long long)s_i[w]; tj += (unsigned long long)s_j[w]; }
        atomicAdd(&ws[0], ti);  // device-scope by default — safe across XCDs
        atomicAdd(&ws[1], tj);
    }
}

__global__ void nz_finalize(const unsigned long long* __restrict__ ws,
                            int* __restrict__ out) {
    if (threadIdx.x == 0 && blockIdx.x == 0) {
        // int64 -> int32 wrap (two's complement), matching numpy astype(np.int32)
        out[0] = (int)(unsigned)(ws[0] & 0xFFFFFFFFull);
        out[1] = (int)(unsigned)(ws[1] & 0xFFFFFFFFull);
    }
}

extern "C" void kernel_launch(void* const* d_in, const int* in_sizes, int n_in,
                              void* d_out, int out_size, void* d_ws, size_t ws_size,
                              hipStream_t stream) {
    const float4* in = (const float4*)d_in[0];
    unsigned long long* ws = (unsigned long long*)d_ws;
    int* out = (int*)d_out;

    // zero the two u64 accumulators every call (deterministic; capture-safe)
    hipMemsetAsync(d_ws, 0, 2 * sizeof(unsigned long long), stream);

    // 2048 blocks x 256 threads = 524288 threads; 32 float4s per thread exactly
    nz_idx_sum_kernel<<<2048, 256, 0, stream>>>(in, ws);
    nz_finalize<<<1, 64, 0, stream>>>(ws, out);
}